// Round 12
// baseline (129.816 us; speedup 1.0000x reference)
//
#include <hip/hip_runtime.h>
#include <hip/hip_fp16.h>

// Bilateral filter, fixed shape: x[16,3,512,512] fp32, K=5, pad=2 reflect.
// sigma_color = sigma_space = 1.1; normalizations cancel in the ratio.
// w = exp2(coef2*d^2 + coef2*sij), coef2 = -log2(e)/2.42.
//
// R9 (4th submit -- prior three rounds were infra timeouts, never ran):
// packed-FP32 verdict: R7 (pk asm + modifiers + pins, absmax 468) AND
// R8 (pk asm, modifier-free, no pins, absmax 4.9) both corrupt => the
// common element, v_pk_*_f32 inline asm, is unusable on gfx950 (consistent
// with hipcc never auto-emitting it: R6 scalarized v2f at VGPR=48).
// ABANDONED. This round gets the same VALU cut via the NATIVE packed path:
// __half2 (v_pk_*_f16 + v_exp_f16), no inline asm anywhere.
//   inner per 2px*tap: hsub2+hmul2+hfma2 (arg) + 2x v_exp_f16 + hfma2+hadd2
//   = 5 pk (10cyc) + 16cyc trans = 26 cyc vs 36 scalar-f32.
// Accum num/den in f16 pairs (den<=25, 24 adds: ~0.1-0.3% err); final
// divide in f32. Error budget ~0.005-0.010 vs threshold 0.0172 (R6 f32
// was 0.0039). Expect dispatch 53.8 -> ~40 us.
//
// One thread = 4x2 tile; window as overlapping __half2 pairs P[6][7]
// (pair = 2 horizontally adjacent taps, aligned with the 2 px of the
// output pair), built once via v_cvt_pkrtz from the f32 window row.
// Center tap (d=0 exactly, w=1 exactly) folded into accumulator init.
// Column reflect (verified R2-R4):
//   w0==0  : col -2 -> c4.z (col 2);  w0==508: col 513 -> c4.y (col 509)
// Row reflect: r = min(abs(r), 2*(H-1)-r).

constexpr int H_ = 512;
constexpr int W_ = 512;

__global__ __launch_bounds__(256, 4) void bilateral_kernel(
    const float* __restrict__ x,
    float* __restrict__ out,
    int nthreads)
{
    int t = blockIdx.x * 256 + threadIdx.x;
    if (t >= nthreads) return;

    int qx = t & 127;          // tile col index (4-wide tiles)
    int rg = (t >> 7) & 255;   // tile row index (2-tall tiles)
    int pl = t >> 15;          // plane (b*C + c)
    int w0 = qx << 2;
    int h0 = rg << 1;
    const float* plane = x + ((long)pl << 18);   // 512*512
    float* oplane = out + ((long)pl << 18);

    int aL = max(w0 - 2, 0);
    int aR = min(w0 + 4, W_ - 2);
    bool bL = (w0 == 0);
    bool bR = (w0 == W_ - 4);

    // P[k][j] = half2(win[k][j], win[k][j+1]), rows h0-2..h0+3,
    // cols w0-2..w0+5. 42 x 32-bit regs (vs 84 for f32 pairs).
    __half2 P[6][7];
#pragma unroll
    for (int k = 0; k < 6; ++k) {
        int r = h0 + k - 2;
        r = min(abs(r), 2 * (H_ - 1) - r);
        const float* rp = plane + r * W_;
        float2 l2 = *(const float2*)(rp + aL);
        float4 c4 = *(const float4*)(rp + w0);
        float2 r2 = *(const float2*)(rp + aR);
        float wr[8];
        wr[0] = bL ? c4.z : l2.x;   // reflect col -2 -> +2
        wr[1] = l2.y;               // col -1 (== col 1 when bL)
        wr[2] = c4.x; wr[3] = c4.y; wr[4] = c4.z; wr[5] = c4.w;
        wr[6] = r2.x;               // col +4 (== col 510 when bR)
        wr[7] = bR ? c4.y : r2.y;   // reflect col 513 -> 509
#pragma unroll
        for (int j = 0; j < 7; ++j)
            P[k][j] = __floats2half2_rn(wr[j], wr[j + 1]);  // v_cvt_pkrtz
    }

    const float coef2 = -0.59615498f;  // -log2(e)/(2*1.21)
    const __half2 k2h = __float2half2_rn(coef2);
    const __half2 one2 = __float2half2_rn(1.0f);

#pragma unroll
    for (int oi = 0; oi < 2; ++oi) {
        __half2 cA = P[oi + 2][2];   // centers: pixels (w0, w0+1)
        __half2 cB = P[oi + 2][4];   // centers: pixels (w0+2, w0+3)
        // Center tap folded exactly: d = pc-pc = 0 in f16, w = 2^0 = 1.
        __half2 numA = cA, denA = one2;
        __half2 numB = cB, denB = one2;
#pragma unroll
        for (int di = 0; di < 5; ++di) {
#pragma unroll
            for (int dj = 0; dj < 5; ++dj) {
                if (di == 2 && dj == 2) continue;   // center handled above
                float csf = coef2 * (float)((di - 2) * (di - 2) +
                                            (dj - 2) * (dj - 2));
                __half2 csh = __float2half2_rn(csf);  // compile-time const
                __half2 pA = P[oi + di][dj];       // direct pair operand
                __half2 pB = P[oi + di][dj + 2];   // pB(dj) == pA(dj+2)
                __half2 dA = __hsub2(pA, cA);      // v_pk_add_f16 (neg)
                __half2 dB = __hsub2(pB, cB);
                __half2 tA = __hmul2(dA, k2h);     // v_pk_mul_f16
                __half2 tB = __hmul2(dB, k2h);
                __half2 aA = __hfma2(tA, dA, csh); // v_pk_fma_f16
                __half2 aB = __hfma2(tB, dB, csh);
                __half2 wA = h2exp2(aA);           // 2x v_exp_f16
                __half2 wB = h2exp2(aB);
                numA = __hfma2(wA, pA, numA);
                denA = __hadd2(denA, wA);
                numB = __hfma2(wB, pB, numB);
                denB = __hadd2(denB, wB);
            }
        }
        // Final divide in f32 for precision.
        float2 nA = __half22float2(numA), dAf = __half22float2(denA);
        float2 nB = __half22float2(numB), dBf = __half22float2(denB);
        float4 o;
        o.x = nA.x * __builtin_amdgcn_rcpf(dAf.x);
        o.y = nA.y * __builtin_amdgcn_rcpf(dAf.y);
        o.z = nB.x * __builtin_amdgcn_rcpf(dBf.x);
        o.w = nB.y * __builtin_amdgcn_rcpf(dBf.y);
        *(float4*)(oplane + (h0 + oi) * W_ + w0) = o;
    }
}

extern "C" void kernel_launch(void* const* d_in, const int* in_sizes, int n_in,
                              void* d_out, int out_size, void* d_ws, size_t ws_size,
                              hipStream_t stream)
{
    const float* x = (const float*)d_in[0];
    float* out = (float*)d_out;
    int nthreads = in_sizes[0] >> 3;         // 8 px per thread (4x2 tile)
    int blocks = (nthreads + 255) / 256;
    bilateral_kernel<<<blocks, 256, 0, stream>>>(x, out, nthreads);
}